// Round 9
// baseline (626.013 us; speedup 1.0000x reference)
//
#include <hip/hip_runtime.h>
#include <hip/hip_bf16.h>
#include <math.h>

#define NN 262144
#define CC 512
#define BB 1024
#define EPSF 1e-5f
#define CAP 512   // LDS spg capacity (nodes/segment); test max ~340, fallback to ws

typedef float f32x4 __attribute__((ext_vector_type(4)));

__device__ __forceinline__ int lower_bound_i(const int* __restrict__ a, int n, int v) {
    int lo = 0, hi = n;
    while (lo < hi) { int mid = (lo + hi) >> 1; if (a[mid] < v) lo = mid + 1; else hi = mid; }
    return lo;
}

__device__ __forceinline__ float sigmoidf(float v) { return 1.0f / (1.0f + __expf(-v)); }

// order-preserving float<->uint for atomicMax
__device__ __forceinline__ unsigned fenc(float f) {
    unsigned b = __float_as_uint(f);
    return (b & 0x80000000u) ? ~b : (b | 0x80000000u);
}
__device__ __forceinline__ float fdec(unsigned k) {
    return __uint_as_float((k & 0x80000000u) ? (k & 0x7fffffffu) : ~k);
}

// fire-and-forget global->LDS (16B/lane, lane-linear LDS dest)
__device__ __forceinline__ void gload16(const float* g, void* l) {
    __builtin_amdgcn_global_load_lds((const __attribute__((address_space(1))) void*)g,
                                     (__attribute__((address_space(3))) void*)l, 16, 0, 0);
}

// DPP reduction steps (fused v_add_f32_dpp / v_max_f32_dpp).
template<int CTRL>
__device__ __forceinline__ float dppAdd(float v) {
    int t = __builtin_amdgcn_update_dpp(0, __float_as_int(v), CTRL, 0xf, 0xf, true);
    return v + __int_as_float(t);
}
template<int CTRL>
__device__ __forceinline__ float dppMax(float v) {
    int t = __builtin_amdgcn_update_dpp(0, __float_as_int(v), CTRL, 0xf, 0xf, true);
    return fmaxf(v, __int_as_float(t));
}

// One block = 2 sequential segments, grid 512. Occupancy is pinned at 1 block/CU
// (128 VGPR = 2 waves/SIMD on the 256-reg/SIMD budget -- R5/R6/R7/R8 evidence),
// so the fix for P1's HBM-latency-bound loop (~900ns/row/wave) is a 4-deep
// global_load_lds ring per wave: 64KB in flight per CU -> throughput-bound.
// Source addresses are pre-swizzled so LDS is lane-linear (conflict-free b128).
__global__ __launch_bounds__(512) void kFused(
    const float* __restrict__ x, const int* __restrict__ batch,
    const float* __restrict__ cweight, const float* __restrict__ cbias,
    const float* __restrict__ sweight, const float* __restrict__ sbias,
    const float* __restrict__ ch_W1, const float* __restrict__ ch_b1,
    const float* __restrict__ ch_W2, const float* __restrict__ ch_b2,
    const float* __restrict__ gn_w, const float* __restrict__ gn_b,
    const float* __restrict__ sp_W1, const float* __restrict__ sp_b1,
    const float* __restrict__ sp_W2, const float* __restrict__ sp_b2,
    const float* __restrict__ init_scale,
    const float* __restrict__ gms, const float* __restrict__ gw,
    const float* __restrict__ gb,
    float* __restrict__ spgOv, float* __restrict__ out)
{
    __shared__ f32x4    stg[8][4][128];                                // 64 KB ring
    __shared__ float    segS1[256], segS2[256], segT1[256], segT2[256]; // 4 KB
    __shared__ unsigned segM[256];                                     // 1 KB
    __shared__ float    spgL[CAP * 16];                                // 32 KB
    __shared__ float    gap[512];                                      // 2 KB
    __shared__ float    part[8][64];                                   // 2 KB
    __shared__ float    hch[64];
    __shared__ float    cA[512];                                       // 2 KB
    __shared__ float    oA[512];                                       // 2 KB

    const int tid  = threadIdx.x;
    const int lane = tid & 63;
    const int w    = tid >> 6;        // 8 waves
    const int g    = lane & 15;
    const int q    = lane >> 4;
    const int h0   = q * 4;
    const int kk   = g & 7;
    const float tau = tanhf(init_scale[0]);
    // pre-swizzled per-lane source offset (floats): c4 of lane (g,q)
    const int swz = g * 32 + q * 4;

    // P1 per-lane weights (loop-invariant)
    float gwv[4], gbv[4], b2v[4], swv[4], sbv[4], w1m[4], w1x[4], w1s[4], w2r[4];
#pragma unroll
    for (int j = 0; j < 4; ++j) {
        const int h = h0 + j;
        gwv[j] = gn_w[g * 16 + h];
        gbv[j] = gn_b[g * 16 + h];
        b2v[j] = sp_b2[h];
        swv[j] = sweight[h];
        sbv[j] = sbias[h];
        w1m[j] = sp_W1[h * 8 + kk];
        w1x[j] = sp_W1[(16 + h) * 8 + kk];
        w1s[j] = sp_W1[(32 + h) * 8 + kk];
        w2r[j] = sp_W2[kk * 16 + h];
    }
    const float b1k = sp_b1[kk];

    const int l2 = lane * 2;
    const int p0 = (lane >> 3) & 1;

    for (int r = 0; r < 2; ++r) {
        const int b = blockIdx.x * 2 + r;
        const int s = lower_bound_i(batch, NN, b);
        const int e = lower_bound_i(batch, NN, b + 1);
        const int cnt = e - s;

        __syncthreads();  // protect LDS from previous segment's P2
        if (tid < 256) {
            segS1[tid] = 0.f; segS2[tid] = 0.f;
            segT1[tid] = 0.f; segT2[tid] = 0.f;
            segM[tid] = fenc(-INFINITY);
        }
        __syncthreads();

        // ---------------- Phase 1: global_load_lds ring (depth 4) ----------------
        float sc1[4] = {0.f,0.f,0.f,0.f}, sc2[4] = {0.f,0.f,0.f,0.f};
        float st1[4] = {0.f,0.f,0.f,0.f}, st2[4] = {0.f,0.f,0.f,0.f};
        float mxc[4] = {-INFINITY,-INFINITY,-INFINITY,-INFINITY};

        if (s + w < e) {
            const int lastn = e - 1;
            // drain prior vmem (P2 stores of prev segment) so vmcnt counting is exact
            asm volatile("s_waitcnt vmcnt(0)" ::: "memory");
            __builtin_amdgcn_sched_barrier(0);
#pragma unroll
            for (int p = 0; p < 4; ++p) {            // uniform 8-instr prologue
                int nr = s + w + 8 * p; if (nr > lastn) nr = lastn;
                const float* rb = x + (size_t)nr * CC + swz;
                gload16(rb,      (void*)&stg[w][p][0]);
                gload16(rb + 16, (void*)&stg[w][p][64]);
            }
            int k = 0;
            for (int n = s + w; n < e; n += 8, ++k) {
                const int sl = k & 3;
                asm volatile("s_waitcnt vmcnt(6)" ::: "memory");  // oldest pair landed
                __builtin_amdgcn_sched_barrier(0);
                const f32x4 c4 = stg[w][sl][lane];
                const f32x4 s4 = stg[w][sl][64 + lane];
                asm volatile("s_waitcnt lgkmcnt(0)" ::: "memory"); // reads done pre-restage
                __builtin_amdgcn_sched_barrier(0);
                {   // re-stage slot with row n+32 (clamped: keeps count uniform)
                    int nr = n + 32; if (nr > lastn) nr = lastn;
                    const float* rb = x + (size_t)nr * CC + swz;
                    gload16(rb,      (void*)&stg[w][sl][0]);
                    gload16(rb + 16, (void*)&stg[w][sl][64]);
                }

                float ca[4] = {c4[0], c4[1], c4[2], c4[3]};
                float sa[4] = {s4[0], s4[1], s4[2], s4[3]};

#pragma unroll
                for (int j = 0; j < 4; ++j) {
                    sc1[j] += ca[j];
                    sc2[j] = fmaf(ca[j], ca[j], sc2[j]);
                    mxc[j] = fmaxf(mxc[j], ca[j]);
                }

                // groupnorm over h (local j + cross-row q)
                float ls = sa[0] + sa[1] + sa[2] + sa[3];
                float lq = fmaf(sa[0], sa[0], fmaf(sa[1], sa[1], fmaf(sa[2], sa[2], sa[3] * sa[3])));
                ls += __shfl_xor(ls, 16); ls += __shfl_xor(ls, 32);
                lq += __shfl_xor(lq, 16); lq += __shfl_xor(lq, 32);
                const float mu   = ls * 0.0625f;
                const float var  = lq * 0.0625f - mu * mu;
                const float rstd = rsqrtf(var + EPSF);
                float xn[4];
#pragma unroll
                for (int j = 0; j < 4; ++j)
                    xn[j] = fmaf((sa[j] - mu) * rstd, gwv[j], gbv[j]);

                // ctx over g: three independent 4-DPP chains (sum, sumsq, max)
                float sm[4], s2c[4], mx[4];
#pragma unroll
                for (int j = 0; j < 4; ++j) {
                    float v = xn[j];
                    v = dppAdd<0xB1>(v); v = dppAdd<0x4E>(v);
                    v = dppAdd<0x124>(v); v = dppAdd<0x128>(v);
                    sm[j] = v;
                    float u = xn[j] * xn[j];
                    u = dppAdd<0xB1>(u); u = dppAdd<0x4E>(u);
                    u = dppAdd<0x124>(u); u = dppAdd<0x128>(u);
                    s2c[j] = u;
                    float m = xn[j];
                    m = dppMax<0xB1>(m); m = dppMax<0x4E>(m);
                    m = dppMax<0x124>(m); m = dppMax<0x128>(m);
                    mx[j] = m;
                }
                float mean[4], stdc[4];
#pragma unroll
                for (int j = 0; j < 4; ++j) {
                    mean[j] = sm[j] * 0.0625f;
                    const float ss = fmaxf(s2c[j] - 16.0f * mean[j] * mean[j], 0.0f);
                    stdc[j] = sqrtf(ss * (1.0f / 15.0f));
                }

                // spatial MLP: partial for k = kk, reduce over q
                float p = 0.f;
#pragma unroll
                for (int j = 0; j < 4; ++j) {
                    p = fmaf(mean[j], w1m[j], p);
                    p = fmaf(mx[j],   w1x[j], p);
                    p = fmaf(stdc[j], w1s[j], p);
                }
                p += __shfl_xor(p, 16); p += __shfl_xor(p, 32);
                const float hsk = fmaxf(p + b1k, 0.0f);

                float spg[4];
#pragma unroll
                for (int j = 0; j < 4; ++j) {
                    float t = hsk * w2r[j];
                    t = dppAdd<0xB1>(t); t = dppAdd<0x4E>(t); t = dppAdd<0x141>(t);
                    spg[j] = fmaf(sigmoidf(t + b2v[j]), 1.0f + swv[j], sbv[j]) + tau;
                }

#pragma unroll
                for (int j = 0; j < 4; ++j) {
                    const float os = spg[j] * sa[j];
                    st1[j] += os;
                    st2[j] = fmaf(os, os, st2[j]);
                }

                if (g == 0) {
                    const int idx = n - s;
                    if (idx < CAP)
                        *(float4*)(&spgL[idx * 16 + h0]) = make_float4(spg[0], spg[1], spg[2], spg[3]);
                    else
                        *(float4*)(spgOv + (size_t)n * 16 + h0) = make_float4(spg[0], spg[1], spg[2], spg[3]);
                }
            }
        }

        // cross-wave accumulation via LDS atomics (once per segment)
        {
            const int ch = g * 16 + h0;
#pragma unroll
            for (int j = 0; j < 4; ++j) {
                atomicAdd(&segS1[ch + j], sc1[j]);
                atomicAdd(&segS2[ch + j], sc2[j]);
                atomicAdd(&segT1[ch + j], st1[j]);
                atomicAdd(&segT2[ch + j], st2[j]);
                atomicMax(&segM[ch + j], fenc(mxc[j]));
            }
        }
        __syncthreads();

        // ---------------- Phase F (inline) ----------------
        const float inv = 1.0f / (float)max(cnt, 1);
        if (tid < 256) {
            gap[tid] = segS1[tid] * inv;
            gap[256 + tid] = (cnt > 0) ? fdec(segM[tid]) : 0.0f;
        }
        __syncthreads();
        {
            const int t = tid & 63, pp = tid >> 6;
            float acc = 0.f;
            for (int i = pp * 64; i < pp * 64 + 64; ++i)
                acc = fmaf(gap[i], ch_W1[i * 64 + t], acc);
            part[pp][t] = acc;
        }
        __syncthreads();
        if (tid < 64) {
            float a = ch_b1[tid];
#pragma unroll
            for (int pp = 0; pp < 8; ++pp) a += part[pp][tid];
            hch[tid] = fmaxf(a, 0.0f);
        }
        __syncthreads();
        if (tid < 256) {
            const int c = tid, gg = c >> 4, h = c & 15;
            float acc = ch_b2[c];
            for (int k = 0; k < 64; ++k) acc = fmaf(hch[k], ch_W2[k * 256 + c], acc);
            const float chg = fmaf(sigmoidf(acc), 1.0f + cweight[h], cbias[h]);
            const float ct = chg + tau;
            const int colc = gg * 32 + h, cols = colc + 16;
            {
                const float S1 = segS1[c], S2 = segS2[c];
                const float m  = ct * S1 * inv;
                const float e2 = ct * ct * S2 * inv;
                const float smv = gms[colc];
                const float gv = fmaxf(e2 - m * m * smv * (2.0f - smv), 0.0f);
                const float A  = gw[colc] * rsqrtf(gv + EPSF);
                cA[colc] = A * ct;
                oA[colc] = gb[colc] - m * smv * A;
            }
            {
                const float T1 = segT1[c], T2 = segT2[c];
                const float m  = T1 * inv;
                const float e2 = T2 * inv;
                const float smv = gms[cols];
                const float gv = fmaxf(e2 - m * m * smv * (2.0f - smv), 0.0f);
                const float A  = gw[cols] * rsqrtf(gv + EPSF);
                cA[cols] = A;
                oA[cols] = gb[cols] - m * smv * A;
            }
        }
        __syncthreads();

        // ---------------- Phase 2 (software-pipelined) ----------------
        const float cf0 = cA[l2],       cf1 = cA[l2 + 1];
        const float cf2 = cA[128 + l2], cf3 = cA[129 + l2];
        const float cf4 = cA[256 + l2], cf5 = cA[257 + l2];
        const float cf6 = cA[384 + l2], cf7 = cA[385 + l2];
        const float of0 = oA[l2],       of1 = oA[l2 + 1];
        const float of2 = oA[128 + l2], of3 = oA[129 + l2];
        const float of4 = oA[256 + l2], of5 = oA[257 + l2];
        const float of6 = oA[384 + l2], of7 = oA[385 + l2];

        float2 xa, xb, xc, xd, sp;
        {
            const int n = s + w;
            if (n < e) {
                const float2* r2 = (const float2*)(x + (size_t)n * CC);
                xa = r2[lane]; xb = r2[64 + lane];
                xc = r2[128 + lane]; xd = r2[192 + lane];
                const int idx = n - s;
                sp = (idx < CAP) ? *(const float2*)(&spgL[idx * 16 + (l2 & 15)])
                                 : *(const float2*)(spgOv + (size_t)n * 16 + (l2 & 15));
            }
        }
        for (int n = s + w; n < e; ) {
            const int nn = n + 8;
            float2 xa2, xb2, xc2, xd2, sp2;
            if (nn < e) {
                const float2* r2 = (const float2*)(x + (size_t)nn * CC);
                xa2 = r2[lane]; xb2 = r2[64 + lane];
                xc2 = r2[128 + lane]; xd2 = r2[192 + lane];
                const int idx = nn - s;
                sp2 = (idx < CAP) ? *(const float2*)(&spgL[idx * 16 + (l2 & 15)])
                                  : *(const float2*)(spgOv + (size_t)nn * 16 + (l2 & 15));
            }

            const float me = p0 ? sp.x : 1.0f;
            const float mo = p0 ? sp.y : 1.0f;

            const float v0 = fmaf(cf0 * me, xa.x, of0);
            const float v1 = fmaf(cf1 * mo, xa.y, of1);
            const float v2 = fmaf(cf2 * me, xb.x, of2);
            const float v3 = fmaf(cf3 * mo, xb.y, of3);
            const float v4 = fmaf(cf4 * me, xc.x, of4);
            const float v5 = fmaf(cf5 * mo, xc.y, of5);
            const float v6 = fmaf(cf6 * me, xd.x, of6);
            const float v7 = fmaf(cf7 * mo, xd.y, of7);

            f32x4* o4 = (f32x4*)(out + (size_t)n * CC);
            f32x4 pa = {v0, v4, v1, v5};
            f32x4 pb = {v2, v6, v3, v7};
            __builtin_nontemporal_store(pa, &o4[lane]);
            __builtin_nontemporal_store(pb, &o4[64 + lane]);

            xa = xa2; xb = xb2; xc = xc2; xd = xd2; sp = sp2;
            n = nn;
        }
    }
}

extern "C" void kernel_launch(void* const* d_in, const int* in_sizes, int n_in,
                              void* d_out, int out_size, void* d_ws, size_t ws_size,
                              hipStream_t stream) {
    (void)in_sizes; (void)n_in; (void)out_size; (void)ws_size;
    const float* x        = (const float*)d_in[0];
    const int*   batch    = (const int*)d_in[1];
    const float* cweight  = (const float*)d_in[3];
    const float* cbias    = (const float*)d_in[4];
    const float* sweight  = (const float*)d_in[5];
    const float* sbias    = (const float*)d_in[6];
    const float* ch_W1    = (const float*)d_in[7];
    const float* ch_b1    = (const float*)d_in[8];
    const float* ch_W2    = (const float*)d_in[9];
    const float* ch_b2    = (const float*)d_in[10];
    const float* gn_w     = (const float*)d_in[11];
    const float* gn_b     = (const float*)d_in[12];
    const float* sp_W1    = (const float*)d_in[13];
    const float* sp_b1    = (const float*)d_in[14];
    const float* sp_W2    = (const float*)d_in[15];
    const float* sp_b2    = (const float*)d_in[16];
    const float* init_sc  = (const float*)d_in[17];
    const float* gnw      = (const float*)d_in[18];
    const float* gnb      = (const float*)d_in[19];
    const float* gms      = (const float*)d_in[20];

    float* spgOv = (float*)d_ws;   // NN*16 floats worst-case overflow
    float* outp  = (float*)d_out;

    kFused<<<BB / 2, 512, 0, stream>>>(x, batch, cweight, cbias, sweight, sbias,
                                       ch_W1, ch_b1, ch_W2, ch_b2, gn_w, gn_b,
                                       sp_W1, sp_b1, sp_W2, sp_b2, init_sc,
                                       gms, gnw, gnb, spgOv, outp);
}

// Round 10
// 462.127 us; speedup vs baseline: 1.3546x; 1.3546x over previous
//
#include <hip/hip_runtime.h>
#include <hip/hip_bf16.h>
#include <math.h>

#define NN 262144
#define CC 512
#define BB 1024
#define EPSF 1e-5f

typedef float f32x4 __attribute__((ext_vector_type(4)));

__device__ __forceinline__ int lower_bound_i(const int* __restrict__ a, int n, int v) {
    int lo = 0, hi = n;
    while (lo < hi) { int mid = (lo + hi) >> 1; if (a[mid] < v) lo = mid + 1; else hi = mid; }
    return lo;
}

__device__ __forceinline__ float sigmoidf(float v) { return 1.0f / (1.0f + __expf(-v)); }

// Fused single-instruction DPP reduction steps (v_add_f32_dpp / v_max_f32_dpp).
// 0xB1 = quad_perm xor1, 0x4E = quad_perm xor2,
// 0x124 = row_ror:4, 0x128 = row_ror:8, 0x141 = row_half_mirror
template<int CTRL>
__device__ __forceinline__ float dppAdd(float v) {
    int t = __builtin_amdgcn_update_dpp(0, __float_as_int(v), CTRL, 0xf, 0xf, true);
    return v + __int_as_float(t);
}
template<int CTRL>
__device__ __forceinline__ float dppMax(float v) {
    int t = __builtin_amdgcn_update_dpp(0, __float_as_int(v), CTRL, 0xf, 0xf, true);
    return fmaxf(v, __int_as_float(t));
}

// ---------------- Kernel A: per-segment pass 1, 2-row ILP --------------------
// Lane map: g = lane&15 (group), q = lane>>4, handles h = 4q..4q+3.
// Each wave processes TWO rows per iteration (independent chains -> 2x ILP/MLP).
__global__ void kA(const float* __restrict__ x, const int* __restrict__ batch,
                   const float* __restrict__ sweight, const float* __restrict__ sbias,
                   const float* __restrict__ gn_w, const float* __restrict__ gn_b,
                   const float* __restrict__ sp_W1, const float* __restrict__ sp_b1,
                   const float* __restrict__ sp_W2, const float* __restrict__ sp_b2,
                   const float* __restrict__ init_scale,
                   float* __restrict__ segS1, float* __restrict__ segMx,
                   float* __restrict__ segS2, float* __restrict__ segT1,
                   float* __restrict__ segT2, int* __restrict__ segCnt,
                   float* __restrict__ spgt)
{
    const int b    = blockIdx.x;
    const int tid  = threadIdx.x;
    const int lane = tid & 63;
    const int w    = tid >> 6;      // 4 waves
    const int g    = lane & 15;
    const int q    = lane >> 4;
    const int h0   = q * 4;
    const int kk   = g & 7;

    __shared__ float red[4][5][256];

    const int s = lower_bound_i(batch, NN, b);
    const int e = lower_bound_i(batch, NN, b + 1);
    const float tau = tanhf(init_scale[0]);

    float gwv[4], gbv[4], b2v[4], swv[4], sbv[4], w1m[4], w1x[4], w1s[4], w2r[4];
#pragma unroll
    for (int j = 0; j < 4; ++j) {
        const int h = h0 + j;
        gwv[j] = gn_w[g * 16 + h];
        gbv[j] = gn_b[g * 16 + h];
        b2v[j] = sp_b2[h];
        swv[j] = sweight[h];
        sbv[j] = sbias[h];
        w1m[j] = sp_W1[h * 8 + kk];
        w1x[j] = sp_W1[(16 + h) * 8 + kk];
        w1s[j] = sp_W1[(32 + h) * 8 + kk];
        w2r[j] = sp_W2[kk * 16 + h];
    }
    const float b1k = sp_b1[kk];

    float sc1[4] = {0.f,0.f,0.f,0.f}, sc2[4] = {0.f,0.f,0.f,0.f};
    float st1[4] = {0.f,0.f,0.f,0.f}, st2[4] = {0.f,0.f,0.f,0.f};
    float mxc[4] = {-INFINITY,-INFINITY,-INFINITY,-INFINITY};

    for (int n0 = s + 2 * w; n0 < e; n0 += 8) {
        const int n1 = (n0 + 1 < e) ? n0 + 1 : e - 1;   // clamped dup on tail
        const bool v1 = (n0 + 1 < e);

        // front-load both rows' loads (4 x 16B in flight)
        const float* r0 = x + (size_t)n0 * CC + g * 32 + h0;
        const float* r1 = x + (size_t)n1 * CC + g * 32 + h0;
        const float4 c4[2] = { *(const float4*)r0, *(const float4*)r1 };
        const float4 s4[2] = { *(const float4*)(r0 + 16), *(const float4*)(r1 + 16) };

        float sa[2][4], spg[2][4];
#pragma unroll
        for (int rr = 0; rr < 2; ++rr) {
            sa[rr][0] = s4[rr].x; sa[rr][1] = s4[rr].y;
            sa[rr][2] = s4[rr].z; sa[rr][3] = s4[rr].w;
        }

        // groupnorm over h (local j + cross-row q): both rows interleaved
        float ls[2], lq[2];
#pragma unroll
        for (int rr = 0; rr < 2; ++rr) {
            ls[rr] = sa[rr][0] + sa[rr][1] + sa[rr][2] + sa[rr][3];
            lq[rr] = fmaf(sa[rr][0], sa[rr][0], fmaf(sa[rr][1], sa[rr][1],
                     fmaf(sa[rr][2], sa[rr][2], sa[rr][3] * sa[rr][3])));
        }
#pragma unroll
        for (int rr = 0; rr < 2; ++rr) {
            ls[rr] += __shfl_xor(ls[rr], 16); ls[rr] += __shfl_xor(ls[rr], 32);
            lq[rr] += __shfl_xor(lq[rr], 16); lq[rr] += __shfl_xor(lq[rr], 32);
        }
        float xn[2][4];
#pragma unroll
        for (int rr = 0; rr < 2; ++rr) {
            const float mu   = ls[rr] * 0.0625f;
            const float var  = lq[rr] * 0.0625f - mu * mu;
            const float rstd = rsqrtf(var + EPSF);
#pragma unroll
            for (int j = 0; j < 4; ++j)
                xn[rr][j] = fmaf((sa[rr][j] - mu) * rstd, gwv[j], gbv[j]);
        }

        // ctx over g: 3 independent 4-DPP chains per row; 2 rows interleave
        float sm[2][4], s2c[2][4], mx[2][4];
#pragma unroll
        for (int rr = 0; rr < 2; ++rr) {
#pragma unroll
            for (int j = 0; j < 4; ++j) {
                float v = xn[rr][j];
                v = dppAdd<0xB1>(v); v = dppAdd<0x4E>(v);
                v = dppAdd<0x124>(v); v = dppAdd<0x128>(v);
                sm[rr][j] = v;
                float u = xn[rr][j] * xn[rr][j];
                u = dppAdd<0xB1>(u); u = dppAdd<0x4E>(u);
                u = dppAdd<0x124>(u); u = dppAdd<0x128>(u);
                s2c[rr][j] = u;
                float m = xn[rr][j];
                m = dppMax<0xB1>(m); m = dppMax<0x4E>(m);
                m = dppMax<0x124>(m); m = dppMax<0x128>(m);
                mx[rr][j] = m;
            }
        }

        // spatial MLP partials, reduce over q, gather over k
        float p[2] = {0.f, 0.f};
#pragma unroll
        for (int rr = 0; rr < 2; ++rr) {
#pragma unroll
            for (int j = 0; j < 4; ++j) {
                const float mean = sm[rr][j] * 0.0625f;
                const float ss   = fmaxf(s2c[rr][j] - 16.0f * mean * mean, 0.0f);
                const float stdc = sqrtf(ss * (1.0f / 15.0f));
                p[rr] = fmaf(mean, w1m[j], p[rr]);
                p[rr] = fmaf(mx[rr][j], w1x[j], p[rr]);
                p[rr] = fmaf(stdc, w1s[j], p[rr]);
            }
        }
#pragma unroll
        for (int rr = 0; rr < 2; ++rr) {
            p[rr] += __shfl_xor(p[rr], 16); p[rr] += __shfl_xor(p[rr], 32);
        }
#pragma unroll
        for (int rr = 0; rr < 2; ++rr) {
            const float hsk = fmaxf(p[rr] + b1k, 0.0f);
#pragma unroll
            for (int j = 0; j < 4; ++j) {
                float t = hsk * w2r[j];
                t = dppAdd<0xB1>(t); t = dppAdd<0x4E>(t); t = dppAdd<0x141>(t);
                spg[rr][j] = fmaf(sigmoidf(t + b2v[j]), 1.0f + swv[j], sbv[j]) + tau;
            }
        }

        // accumulate row0 (always) + row1 (if real)
#pragma unroll
        for (int j = 0; j < 4; ++j) {
            const float ca0 = ((const float*)&c4[0])[j];
            sc1[j] += ca0;
            sc2[j] = fmaf(ca0, ca0, sc2[j]);
            mxc[j] = fmaxf(mxc[j], ca0);
            const float os0 = spg[0][j] * sa[0][j];
            st1[j] += os0;
            st2[j] = fmaf(os0, os0, st2[j]);
        }
        if (g == 0)
            *(float4*)(spgt + (size_t)n0 * 16 + h0) =
                make_float4(spg[0][0], spg[0][1], spg[0][2], spg[0][3]);
        if (v1) {
#pragma unroll
            for (int j = 0; j < 4; ++j) {
                const float ca1 = ((const float*)&c4[1])[j];
                sc1[j] += ca1;
                sc2[j] = fmaf(ca1, ca1, sc2[j]);
                mxc[j] = fmaxf(mxc[j], ca1);
                const float os1 = spg[1][j] * sa[1][j];
                st1[j] += os1;
                st2[j] = fmaf(os1, os1, st2[j]);
            }
            if (g == 0)
                *(float4*)(spgt + (size_t)n1 * 16 + h0) =
                    make_float4(spg[1][0], spg[1][1], spg[1][2], spg[1][3]);
        }
    }

    const int ch = g * 16 + h0;
    *(float4*)&red[w][0][ch] = make_float4(sc1[0], sc1[1], sc1[2], sc1[3]);
    *(float4*)&red[w][1][ch] = make_float4(mxc[0], mxc[1], mxc[2], mxc[3]);
    *(float4*)&red[w][2][ch] = make_float4(sc2[0], sc2[1], sc2[2], sc2[3]);
    *(float4*)&red[w][3][ch] = make_float4(st1[0], st1[1], st1[2], st1[3]);
    *(float4*)&red[w][4][ch] = make_float4(st2[0], st2[1], st2[2], st2[3]);
    __syncthreads();
    if (tid < 256) {
        const int c = tid;
        float a0 = red[0][0][c] + red[1][0][c] + red[2][0][c] + red[3][0][c];
        float a1 = fmaxf(fmaxf(red[0][1][c], red[1][1][c]), fmaxf(red[2][1][c], red[3][1][c]));
        float a2 = red[0][2][c] + red[1][2][c] + red[2][2][c] + red[3][2][c];
        float a3 = red[0][3][c] + red[1][3][c] + red[2][3][c] + red[3][3][c];
        float a4 = red[0][4][c] + red[1][4][c] + red[2][4][c] + red[3][4][c];
        segS1[b * 256 + c] = a0;
        segMx[b * 256 + c] = a1;
        segS2[b * 256 + c] = a2;
        segT1[b * 256 + c] = a3;
        segT2[b * 256 + c] = a4;
    }
    if (tid == 0) segCnt[b] = e - s;
}

// ---------------- Kernel F: per-segment finalize -----------------------------
__global__ void kF(const float* __restrict__ segS1, const float* __restrict__ segMx,
                   const float* __restrict__ segS2, const float* __restrict__ segT1,
                   const float* __restrict__ segT2, const int* __restrict__ segCnt,
                   const float* __restrict__ ch_W1, const float* __restrict__ ch_b1,
                   const float* __restrict__ ch_W2, const float* __restrict__ ch_b2,
                   const float* __restrict__ cweight, const float* __restrict__ cbias,
                   const float* __restrict__ init_scale,
                   const float* __restrict__ gms, const float* __restrict__ gw,
                   const float* __restrict__ gb,
                   float* __restrict__ coef, float* __restrict__ offs)
{
    const int b = blockIdx.x;
    const int tid = threadIdx.x;
    __shared__ float gap[512];
    __shared__ float hch[64];
    __shared__ float part[4][64];

    const int cnt = segCnt[b];
    const float inv = 1.0f / (float)max(cnt, 1);
    if (tid < 256) {
        gap[tid] = segS1[b * 256 + tid] * inv;
        const float m = segMx[b * 256 + tid];
        gap[256 + tid] = (cnt > 0) ? m : 0.0f;
    }
    __syncthreads();
    {
        const int t = tid & 63, pp = tid >> 6;
        float acc = 0.f;
        for (int i = pp * 128; i < pp * 128 + 128; ++i)
            acc = fmaf(gap[i], ch_W1[i * 64 + t], acc);
        part[pp][t] = acc;
    }
    __syncthreads();
    if (tid < 64)
        hch[tid] = fmaxf(part[0][tid] + part[1][tid] + part[2][tid] + part[3][tid] + ch_b1[tid], 0.0f);
    __syncthreads();
    if (tid < 256) {
        const int c = tid, gg = c >> 4, h = c & 15;
        float acc = ch_b2[c];
        for (int k = 0; k < 64; ++k) acc = fmaf(hch[k], ch_W2[k * 256 + c], acc);
        const float chg = fmaf(sigmoidf(acc), 1.0f + cweight[h], cbias[h]);
        const float tau = tanhf(init_scale[0]);
        const float ct = chg + tau;
        const int colc = gg * 32 + h, cols = colc + 16;
        {
            const float S1 = segS1[b * 256 + c], S2 = segS2[b * 256 + c];
            const float m  = ct * S1 * inv;
            const float e2 = ct * ct * S2 * inv;
            const float smv = gms[colc];
            const float gv = fmaxf(e2 - m * m * smv * (2.0f - smv), 0.0f);
            const float A  = gw[colc] * rsqrtf(gv + EPSF);
            coef[b * 512 + colc] = A * ct;
            offs[b * 512 + colc] = gb[colc] - m * smv * A;
        }
        {
            const float T1 = segT1[b * 256 + c], T2 = segT2[b * 256 + c];
            const float m  = T1 * inv;
            const float e2 = T2 * inv;
            const float smv = gms[cols];
            const float gv = fmaxf(e2 - m * m * smv * (2.0f - smv), 0.0f);
            const float A  = gw[cols] * rsqrtf(gv + EPSF);
            coef[b * 512 + cols] = A;
            offs[b * 512 + cols] = gb[cols] - m * smv * A;
        }
    }
}

// ---------------- Kernel B: streaming final write, 2-row ILP -----------------
// Reverse order (kA's tail of x L3-resident) + nontemporal stores.
__global__ void kB(const float* __restrict__ x, const int* __restrict__ batch,
                   const float* __restrict__ coef, const float* __restrict__ offs,
                   const float* __restrict__ spgt, float* __restrict__ out)
{
    const int b = BB - 1 - blockIdx.x;
    const int tid = threadIdx.x;
    const int lane = tid & 63, w = tid >> 6;
    const int l2 = lane * 2;
    const int p0 = (lane >> 3) & 1;

    const int s = lower_bound_i(batch, NN, b);
    const int e = lower_bound_i(batch, NN, b + 1);

    const float* cfb = coef + (size_t)b * 512;
    const float* ofb = offs + (size_t)b * 512;
    const float cf0 = cfb[l2],       cf1 = cfb[l2 + 1];
    const float cf2 = cfb[128 + l2], cf3 = cfb[129 + l2];
    const float cf4 = cfb[256 + l2], cf5 = cfb[257 + l2];
    const float cf6 = cfb[384 + l2], cf7 = cfb[385 + l2];
    const float of0 = ofb[l2],       of1 = ofb[l2 + 1];
    const float of2 = ofb[128 + l2], of3 = ofb[129 + l2];
    const float of4 = ofb[256 + l2], of5 = ofb[257 + l2];
    const float of6 = ofb[384 + l2], of7 = ofb[385 + l2];

    for (int n0 = s + 2 * w; n0 < e; n0 += 8) {
        const int n1 = (n0 + 1 < e) ? n0 + 1 : e - 1;
        const bool v1 = (n0 + 1 < e);

        const float2* r0 = (const float2*)(x + (size_t)n0 * CC);
        const float2* r1 = (const float2*)(x + (size_t)n1 * CC);
        const float2 xa[2] = { r0[lane],        r1[lane] };
        const float2 xb[2] = { r0[64 + lane],   r1[64 + lane] };
        const float2 xc[2] = { r0[128 + lane],  r1[128 + lane] };
        const float2 xd[2] = { r0[192 + lane],  r1[192 + lane] };
        const float2 sp[2] = {
            *(const float2*)(spgt + (size_t)n0 * 16 + (l2 & 15)),
            *(const float2*)(spgt + (size_t)n1 * 16 + (l2 & 15)) };

#pragma unroll
        for (int rr = 0; rr < 2; ++rr) {
            if (rr == 1 && !v1) break;
            const float me = p0 ? sp[rr].x : 1.0f;
            const float mo = p0 ? sp[rr].y : 1.0f;

            const float v0 = fmaf(cf0 * me, xa[rr].x, of0);
            const float v1f = fmaf(cf1 * mo, xa[rr].y, of1);
            const float v2 = fmaf(cf2 * me, xb[rr].x, of2);
            const float v3 = fmaf(cf3 * mo, xb[rr].y, of3);
            const float v4 = fmaf(cf4 * me, xc[rr].x, of4);
            const float v5 = fmaf(cf5 * mo, xc[rr].y, of5);
            const float v6 = fmaf(cf6 * me, xd[rr].x, of6);
            const float v7 = fmaf(cf7 * mo, xd[rr].y, of7);

            f32x4* o4 = (f32x4*)(out + (size_t)(rr ? n1 : n0) * CC);
            f32x4 pa = {v0, v4, v1f, v5};
            f32x4 pb = {v2, v6, v3, v7};
            __builtin_nontemporal_store(pa, &o4[lane]);
            __builtin_nontemporal_store(pb, &o4[64 + lane]);
        }
    }
}

extern "C" void kernel_launch(void* const* d_in, const int* in_sizes, int n_in,
                              void* d_out, int out_size, void* d_ws, size_t ws_size,
                              hipStream_t stream) {
    (void)in_sizes; (void)n_in; (void)out_size; (void)ws_size;
    const float* x        = (const float*)d_in[0];
    const int*   batch    = (const int*)d_in[1];
    const float* cweight  = (const float*)d_in[3];
    const float* cbias    = (const float*)d_in[4];
    const float* sweight  = (const float*)d_in[5];
    const float* sbias    = (const float*)d_in[6];
    const float* ch_W1    = (const float*)d_in[7];
    const float* ch_b1    = (const float*)d_in[8];
    const float* ch_W2    = (const float*)d_in[9];
    const float* ch_b2    = (const float*)d_in[10];
    const float* gn_w     = (const float*)d_in[11];
    const float* gn_b     = (const float*)d_in[12];
    const float* sp_W1    = (const float*)d_in[13];
    const float* sp_b1    = (const float*)d_in[14];
    const float* sp_W2    = (const float*)d_in[15];
    const float* sp_b2    = (const float*)d_in[16];
    const float* init_sc  = (const float*)d_in[17];
    const float* gnw      = (const float*)d_in[18];
    const float* gnb      = (const float*)d_in[19];
    const float* gms      = (const float*)d_in[20];

    float* ws    = (float*)d_ws;
    float* segS1 = ws;                        // BB*256
    float* segMx = segS1 + BB * 256;
    float* segS2 = segMx + BB * 256;
    float* segT1 = segS2 + BB * 256;
    float* segT2 = segT1 + BB * 256;
    int*   segCnt = (int*)(segT2 + BB * 256); // BB
    float* coef  = (float*)(segCnt + BB);     // BB*512
    float* offs  = coef + BB * 512;           // BB*512
    float* spgt  = offs + BB * 512;           // NN*16
    float* outp  = (float*)d_out;

    kA<<<BB, 256, 0, stream>>>(x, batch, sweight, sbias, gn_w, gn_b,
                               sp_W1, sp_b1, sp_W2, sp_b2, init_sc,
                               segS1, segMx, segS2, segT1, segT2, segCnt, spgt);
    kF<<<BB, 256, 0, stream>>>(segS1, segMx, segS2, segT1, segT2, segCnt,
                               ch_W1, ch_b1, ch_W2, ch_b2, cweight, cbias,
                               init_sc, gms, gnw, gnb, coef, offs);
    kB<<<BB, 256, 0, stream>>>(x, batch, coef, offs, spgt, outp);
}